// Round 6
// baseline (151.869 us; speedup 1.0000x reference)
//
#include <hip/hip_runtime.h>
#include <math.h>

// Problem constants
#define BB 8
#define LL 1024
#define SS 1024
#define CC 128
#define NN 8
#define PP 256

static constexpr float EPS       = 1e-6f;
static constexpr float ONE_M_EPS = 1.0f - 1e-6f;
static constexpr float INV_T     = 1.0f / 0.07f;
static constexpr float NLL_MAX   = 13.815511f;    // -log(1e-6)
static constexpr float NLL_MIN   = 1.0000005e-6f; // -log(1-1e-6)

// Workspace layout (float offsets)
static constexpr size_t DOTSZ      = (size_t)BB * LL * SS;   // 8388608
static constexpr size_t OFF_LSER   = DOTSZ;                  // B*L
static constexpr size_t OFF_LSEC   = DOTSZ + 16384;          // B*S
static constexpr size_t OFF_SHARP2 = DOTSZ + 32768;          // B*L
static constexpr size_t OFF_RP     = DOTSZ + 40960;          // rowpart: 8*16*1024*4
static constexpr size_t OFF_CP     = OFF_RP + 524288;        // colpart: 8*16*1024*4
static constexpr size_t OFF_ACC    = OFF_CP + 524288;        // B*6
static constexpr size_t OFF_ACCCL  = OFF_ACC + 48;           // 2
static constexpr size_t OFF_QN     = OFF_ACC + 64;           // 8*128 normalized q_sel
// Pre-split bf16 hi/lo planes. Per row: 4 ksteps x [16 floats hi | 16 floats lo] = 128 float slots.
static constexpr size_t OFF_ASP    = OFF_ACC + 2048;         // 8*1024*128 = 1048576
static constexpr size_t OFF_BSP    = OFF_ASP + 1048576;      // 1048576

// Output layout (floats): sharp1[8192], cl_pos_save[1024], scalars
static constexpr int OUT_CLSAVE = 8192;
static constexpr int OUT_SCAL   = 9216;

typedef __bf16 bf16x8 __attribute__((ext_vector_type(8)));
typedef float  floatx4 __attribute__((ext_vector_type(4)));

// Split 4 fp32 into packed bf16 hi pairs (RNE) + lo pairs (exact residual, truncated).
__device__ __forceinline__ void split_f4(float4 x,
                                         unsigned& hp0, unsigned& hp1,
                                         unsigned& lp0, unsigned& lp1) {
    unsigned u0 = __builtin_bit_cast(unsigned, x.x);
    unsigned u1 = __builtin_bit_cast(unsigned, x.y);
    unsigned u2 = __builtin_bit_cast(unsigned, x.z);
    unsigned u3 = __builtin_bit_cast(unsigned, x.w);
    unsigned r0 = u0 + 0x7FFFu + ((u0 >> 16) & 1u);
    unsigned r1 = u1 + 0x7FFFu + ((u1 >> 16) & 1u);
    unsigned r2 = u2 + 0x7FFFu + ((u2 >> 16) & 1u);
    unsigned r3 = u3 + 0x7FFFu + ((u3 >> 16) & 1u);
    float s0 = x.x - __builtin_bit_cast(float, r0 & 0xFFFF0000u);
    float s1 = x.y - __builtin_bit_cast(float, r1 & 0xFFFF0000u);
    float s2 = x.z - __builtin_bit_cast(float, r2 & 0xFFFF0000u);
    float s3 = x.w - __builtin_bit_cast(float, r3 & 0xFFFF0000u);
    hp0 = __builtin_amdgcn_perm(r1, r0, 0x07060302u);
    hp1 = __builtin_amdgcn_perm(r3, r2, 0x07060302u);
    lp0 = __builtin_amdgcn_perm(__builtin_bit_cast(unsigned, s1),
                                __builtin_bit_cast(unsigned, s0), 0x07060302u);
    lp1 = __builtin_amdgcn_perm(__builtin_bit_cast(unsigned, s3),
                                __builtin_bit_cast(unsigned, s2), 0x07060302u);
}

// ---------------- K0: presplit A,B into bf16 hi/lo planes (blocks 0..1023) + prep (block 1024) ----
__global__ __launch_bounds__(256) void presplit(const float* __restrict__ A,
                                                const float* __restrict__ Bm,
                                                const float* __restrict__ q_cl,
                                                const float* __restrict__ cl_pos,
                                                const int* __restrict__ idx,
                                                float* __restrict__ out,
                                                float* __restrict__ ws) {
    int tid = threadIdx.x;
    if (blockIdx.x == 1024) {
        int lane = tid & 63, w = tid >> 6;
        if (tid < 52) ws[OFF_ACC + tid] = 0.0f;
        for (int n = w; n < NN; n += 4) {
            int in = idx[n];
            const float* q = q_cl + ((size_t)(n * PP + in)) * CC;
            float2 qv = *(const float2*)(q + 2 * lane);
            float ss = qv.x * qv.x + qv.y * qv.y;
            for (int o = 32; o; o >>= 1) ss += __shfl_xor(ss, o);
            float inv = 1.0f / fmaxf(sqrtf(ss), 1e-12f);
            *(float2*)(ws + OFF_QN + n * 128 + 2 * lane) = make_float2(qv.x * inv, qv.y * inv);
            const float* cp = cl_pos + ((size_t)(n * PP + in)) * CC;
            float2 cv = *(const float2*)(cp + 2 * lane);
            *(float2*)(out + OUT_CLSAVE + n * 128 + 2 * lane) = cv;
        }
        return;
    }
    int bb  = blockIdx.x;
    int mat = bb >> 9;                                   // 0=A, 1=B
    size_t grow = (size_t)(bb & 511) * 16 + (tid >> 4);  // global row 0..8191 (= b*1024+row)
    int c   = tid & 15;                                  // 8-elem chunk within row
    const float* in = (mat ? Bm : A) + grow * CC + c * 8;
    float4 v0 = *(const float4*)in;
    float4 v1 = *(const float4*)(in + 4);
    unsigned h0, h1, l0, l1, h2, h3, l2, l3;
    split_f4(v0, h0, h1, l0, l1);
    split_f4(v1, h2, h3, l2, l3);
    // row layout: [ks=c>>2][hi 16 floats | lo 16 floats]; chunk cc=c&3 is 4 floats (16B = 8 bf16)
    float* outp = ws + (mat ? OFF_BSP : OFF_ASP) + grow * 128 + (size_t)(c >> 2) * 32 + (c & 3) * 4;
    *(uint4*)outp        = make_uint4(h0, h1, h2, h3);
    *(uint4*)(outp + 16) = make_uint4(l0, l1, l2, l3);
}

// ---------------- K1: LDS-tiled GEMM on pre-split bf16 (512 blocks) ----------------
// 128x128 tile/block, 4 waves (64x64 each), BK=32, double-buffered 2x32KB LDS.
// LDS per matrix buffer: [128 rows][8 chunks of 16B], phys_chunk = logical ^ (row&7).
__global__ __launch_bounds__(256, 2) void gemm_dot(float* __restrict__ dot,
                                                   float* __restrict__ ws) {
    __shared__ __align__(16) char lds[2][32768];   // [dbuf][A 16KB | B 16KB]

    int tid  = threadIdx.x;
    int lane = tid & 63;
    int w    = tid >> 6;

    int t  = blockIdx.x;            // 0..511
    int b  = t >> 6;
    int rm = t & 63;
    int bl = rm >> 3, bs = rm & 7;
    int R0 = bl * 128, C0 = bs * 128;

    const float* Ab = ws + OFF_ASP + ((size_t)(b * 1024 + R0)) * 128;
    const float* Bb = ws + OFF_BSP + ((size_t)(b * 1024 + C0)) * 128;

    // staging: 2048 16B-chunks per kstep (A 1024 + B 1024), 8 per thread.
    // LDS linear dst = g*16; source pre-permuted so that phys chunk pc holds logical pc^(row&7).
    const float* srcp[8];
    int ldsb[8];
#pragma unroll
    for (int i = 0; i < 8; i++) {
        int g   = i * 256 + tid;
        int mat = g >> 10;
        int r   = (g >> 3) & 127;
        int pc  = g & 7;
        int c   = pc ^ (r & 7);
        srcp[i] = (mat ? Bb : Ab) + (size_t)r * 128 + (c >> 2) * 16 + (c & 3) * 4;
        ldsb[i] = g * 16;
    }

    int fl   = lane & 15;
    int quad = lane >> 4;
    int wr   = w >> 1, wc = w & 1;
    int Rw   = wr * 64, Cw = wc * 64;

    floatx4 acc[4][4];
#pragma unroll
    for (int i = 0; i < 4; i++)
#pragma unroll
        for (int j = 0; j < 4; j++) acc[i][j] = (floatx4){0.f, 0.f, 0.f, 0.f};

    uint4 rg[8];
    // prologue: stage kstep 0
#pragma unroll
    for (int i = 0; i < 8; i++) rg[i] = *(const uint4*)(srcp[i]);
#pragma unroll
    for (int i = 0; i < 8; i++) *(uint4*)(&lds[0][ldsb[i]]) = rg[i];
    __syncthreads();

    for (int ks = 0; ks < 4; ks++) {
        int cur = ks & 1;
        if (ks < 3) {
#pragma unroll
            for (int i = 0; i < 8; i++)
                rg[i] = *(const uint4*)(srcp[i] + (ks + 1) * 32);
        }
        const char* la = lds[cur];
        const char* lb = lds[cur] + 16384;
        bf16x8 ah[4], al[4];
#pragma unroll
        for (int mt = 0; mt < 4; mt++) {
            int row = Rw + mt * 16 + fl;
            int sw  = row & 7;
            ah[mt] = *(const bf16x8*)(la + row * 128 + ((quad ^ sw) * 16));
            al[mt] = *(const bf16x8*)(la + row * 128 + (((quad + 4) ^ sw) * 16));
        }
#pragma unroll
        for (int nt = 0; nt < 4; nt++) {
            int row = Cw + nt * 16 + fl;
            int sw  = row & 7;
            bf16x8 bh  = *(const bf16x8*)(lb + row * 128 + ((quad ^ sw) * 16));
            bf16x8 blo = *(const bf16x8*)(lb + row * 128 + (((quad + 4) ^ sw) * 16));
#pragma unroll
            for (int mt = 0; mt < 4; mt++) {
                acc[mt][nt] = __builtin_amdgcn_mfma_f32_16x16x32_bf16(ah[mt], bh,  acc[mt][nt], 0, 0, 0);
                acc[mt][nt] = __builtin_amdgcn_mfma_f32_16x16x32_bf16(ah[mt], blo, acc[mt][nt], 0, 0, 0);
                acc[mt][nt] = __builtin_amdgcn_mfma_f32_16x16x32_bf16(al[mt], bh,  acc[mt][nt], 0, 0, 0);
            }
        }
        if (ks < 3) {
            char* nxt = lds[cur ^ 1];
#pragma unroll
            for (int i = 0; i < 8; i++) *(uint4*)(&nxt[ldsb[i]]) = rg[i];
        }
        __syncthreads();
    }

    // ---- Store dot tile. C/D layout: col=lane&15, row=quad*4+reg ----
#pragma unroll
    for (int mt = 0; mt < 4; mt++)
#pragma unroll
        for (int nt = 0; nt < 4; nt++) {
            int col = C0 + Cw + nt * 16 + fl;
#pragma unroll
            for (int r = 0; r < 4; r++) {
                int row = R0 + Rw + mt * 16 + quad * 4 + r;
                dot[((size_t)(b * 1024 + row)) * 1024 + col] = acc[mt][nt][r];
            }
        }

    // ---- Fused wave-private tile statistics (64x64 per wave) ----
    int stile = bs * 2 + wc;
    int ltile = bl * 2 + wr;
    float ces[4], cmx[4], csm[4], csq[4];
#pragma unroll
    for (int nt = 0; nt < 4; nt++) { ces[nt] = 0.f; cmx[nt] = -1e30f; csm[nt] = 0.f; csq[nt] = 0.f; }
#pragma unroll
    for (int mt = 0; mt < 4; mt++) {
#pragma unroll
        for (int r = 0; r < 4; r++) {
            float es = 0.f, mx = -1e30f, sm = 0.f, sq = 0.f;
#pragma unroll
            for (int nt = 0; nt < 4; nt++) {
                float d  = acc[mt][nt][r];
                float e  = __expf(d * INV_T);
                float s2 = fmaf(0.5f, d, 0.5f);
                es += e; mx = fmaxf(mx, s2); sm += s2; sq += s2 * s2;
                ces[nt] += e; cmx[nt] = fmaxf(cmx[nt], s2); csm[nt] += s2; csq[nt] += s2 * s2;
            }
            for (int o = 1; o < 16; o <<= 1) {
                es += __shfl_xor(es, o);
                mx = fmaxf(mx, __shfl_xor(mx, o));
                sm += __shfl_xor(sm, o);
                sq += __shfl_xor(sq, o);
            }
            if (fl == 0) {
                int row = R0 + Rw + mt * 16 + quad * 4 + r;
                *(float4*)(ws + OFF_RP + (((size_t)(b * 16 + stile)) * 1024 + row) * 4) =
                    make_float4(es, mx, sm, sq);
            }
        }
    }
#pragma unroll
    for (int nt = 0; nt < 4; nt++) {
        float es = ces[nt], mx = cmx[nt], sm = csm[nt], sq = csq[nt];
        for (int o = 16; o < 64; o <<= 1) {
            es += __shfl_xor(es, o);
            mx = fmaxf(mx, __shfl_xor(mx, o));
            sm += __shfl_xor(sm, o);
            sq += __shfl_xor(sq, o);
        }
        if (quad == 0) {
            int col = C0 + Cw + nt * 16 + fl;
            *(float4*)(ws + OFF_CP + (((size_t)(b * 16 + ltile)) * 1024 + col) * 4) =
                make_float4(es, mx, sm, sq);
        }
    }
}

// ---------------- K2: blocks 0..15 combine+softmax; blocks 16..527 contrast ----------------
__global__ __launch_bounds__(256) void mid(const float* __restrict__ cl_pos,
                                           const int* __restrict__ idx,
                                           float* __restrict__ ws,
                                           float* __restrict__ out) {
    int q   = blockIdx.x;
    int tid = threadIdx.x;
    int lane = tid & 63, wid = tid >> 6;

    if (q < 16) {
        bool docol = (q < 8);
        int b = q & 7;
        const float* part = ws + (docol ? OFF_CP : OFF_RP);
        float* lse = ws + (docol ? OFF_LSEC : OFF_LSER) + (size_t)b * 1024;
        float zs[4];
        float mxall = -1e30f;
#pragma unroll
        for (int r = 0; r < 4; r++) {
            int i = tid + r * 256;
            float es = 0.f, mx = -1e30f, sm = 0.f, sq = 0.f;
#pragma unroll
            for (int t = 0; t < 16; t++) {
                float4 v = *(const float4*)(part + (((size_t)(b * 16 + t)) * 1024 + i) * 4);
                es += v.x; mx = fmaxf(mx, v.y); sm += v.z; sq += v.w;
            }
            float mean = sm * (1.0f / 1024.0f);
            float var  = (sq - sm * sm * (1.0f / 1024.0f)) * (1.0f / 1023.0f);
            zs[r] = (mx - mean) / sqrtf(fmaxf(var, 1e-30f));
            mxall = fmaxf(mxall, zs[r]);
            lse[i] = __logf(es);
        }
        __shared__ float sb[4];
        __shared__ float red;
        float mx = mxall;
        for (int o = 32; o; o >>= 1) mx = fmaxf(mx, __shfl_xor(mx, o));
        if (!lane) sb[wid] = mx;
        __syncthreads();
        if (tid == 0) red = fmaxf(fmaxf(sb[0], sb[1]), fmaxf(sb[2], sb[3]));
        __syncthreads();
        mx = red;
        float e[4]; float smv = 0.f;
#pragma unroll
        for (int r = 0; r < 4; r++) { e[r] = __expf(zs[r] - mx); smv += e[r]; }
        for (int o = 32; o; o >>= 1) smv += __shfl_xor(smv, o);
        __syncthreads();
        if (!lane) sb[wid] = smv;
        __syncthreads();
        if (tid == 0) red = sb[0] + sb[1] + sb[2] + sb[3];
        __syncthreads();
        float inv = 1.0f / red;
        float* dst = docol ? (out + (size_t)b * 1024) : (ws + OFF_SHARP2 + (size_t)b * 1024);
#pragma unroll
        for (int r = 0; r < 4; r++) dst[tid + r * 256] = e[r] * inv;
    } else {
        // ---- contrast: one wave per all_k row j ----
        int j = (q - 16) * 4 + wid;
        int m, p;
        if (j < NN) {
            m = j; p = idx[j];
        } else {
            int jj = j - NN;
            m = jj / (PP - 1);
            p = 1 + (jj - m * (PP - 1));
            if (p == idx[m]) p = 0;
        }
        const float* k = cl_pos + ((size_t)(m * PP + p)) * CC;
        float2 kv = *(const float2*)(k + 2 * lane);
        float ksq = kv.x * kv.x + kv.y * kv.y;
        for (int o = 32; o; o >>= 1) ksq += __shfl_xor(ksq, o);
        float invkn = 1.0f / fmaxf(sqrtf(ksq), 1e-12f);
        float pos = 0.0f, neg = 0.0f;
        if (j < NN) {
            const float2 qv = *(const float2*)(ws + OFF_QN + j * 128 + 2 * lane);
            float dt = qv.x * kv.x + qv.y * kv.y;
            for (int o = 32; o; o >>= 1) dt += __shfl_xor(dt, o);
            float sim = fminf(fmaxf(fmaf(0.5f * invkn, dt, 0.5f), EPS), ONE_M_EPS);
            pos = -__logf(sim);
        } else {
#pragma unroll
            for (int n = 0; n < NN; n++) {
                const float2 qv = *(const float2*)(ws + OFF_QN + n * 128 + 2 * lane);
                float dt = qv.x * kv.x + qv.y * kv.y;
                for (int o = 32; o; o >>= 1) dt += __shfl_xor(dt, o);
                float om = fminf(fmaxf(fmaf(-0.5f * invkn, dt, 0.5f), EPS), ONE_M_EPS);
                neg -= __logf(om);
            }
        }
        __shared__ float cb[2][4];
        if (!lane) { cb[0][wid] = pos; cb[1][wid] = neg; }
        __syncthreads();
        if (tid == 0) {
            float ps = cb[0][0] + cb[0][1] + cb[0][2] + cb[0][3];
            float ng = cb[1][0] + cb[1][1] + cb[1][2] + cb[1][3];
            if (ps != 0.0f) atomicAdd(ws + OFF_ACCCL + 0, ps);
            if (ng != 0.0f) atomicAdd(ws + OFF_ACCCL + 1, ng);
        }
    }
}

// ---------------- K3: main elementwise loss (branchless) ----------------
__device__ __forceinline__ void proc_elem(float d, int lab, float lcj, float sh1j,
                                          float lr, float s2v,
                                          float& posg, float& negg, float& l1, float& l2,
                                          float& negs, float& pcf) {
    float t = lr + lcj - d * (2.0f * INV_T);   // -log(conf_geo)
    float isPos = (lab == 1) ? 1.0f : 0.0f;
    float isNeg = 1.0f - isPos;
    float tp   = fminf(fmaxf(t, NLL_MIN), NLL_MAX);
    float simc = fminf(fmaxf(fmaf(0.5f, d, 0.5f), EPS), ONE_M_EPS);
    float om   = fminf(fmaxf(fmaf(-0.5f, d, 0.5f), EPS), ONE_M_EPS);   // 1-simc exactly
    float nll2 = -__logf(simc);
    float cf   = fminf(fmaxf(__expf(-t), EPS), ONE_M_EPS);
    float nllg = -__logf(1.0f - cf);
    float nlls = -__logf(om);
    posg += isPos * tp;
    l1   += isPos * nll2 * sh1j;
    l2   += isPos * nll2 * s2v;
    pcf  += isPos;
    negg += isNeg * nllg;
    negs += isNeg * nlls;
}

__global__ __launch_bounds__(256) void main_loss(const float* __restrict__ dot,
                                                 const int* __restrict__ label,
                                                 const float* __restrict__ sharp1,
                                                 float* __restrict__ ws) {
    int b = blockIdx.y;
    int l0 = blockIdx.x * 4;
    int s = threadIdx.x * 4;
    float4 lc4 = *(const float4*)(ws + OFF_LSEC + (size_t)b * 1024 + s);
    float4 sh1 = *(const float4*)(sharp1 + (size_t)b * 1024 + s);
    const float* lser = ws + OFF_LSER + (size_t)b * 1024;
    const float* sh2  = ws + OFF_SHARP2 + (size_t)b * 1024;
    float posg = 0, negg = 0, l1 = 0, l2 = 0, negs = 0, pcf = 0;
#pragma unroll
    for (int r = 0; r < 4; r++) {
        int l = l0 + r;
        float lr  = lser[l];
        float s2v = sh2[l];
        size_t base = ((size_t)(b * 1024 + l)) * 1024 + s;
        float4 d4 = *(const float4*)(dot + base);
        int4  lb  = *(const int4*)(label + base);
        proc_elem(d4.x, lb.x, lc4.x, sh1.x, lr, s2v, posg, negg, l1, l2, negs, pcf);
        proc_elem(d4.y, lb.y, lc4.y, sh1.y, lr, s2v, posg, negg, l1, l2, negs, pcf);
        proc_elem(d4.z, lb.z, lc4.z, sh1.z, lr, s2v, posg, negg, l1, l2, negs, pcf);
        proc_elem(d4.w, lb.w, lc4.w, sh1.w, lr, s2v, posg, negg, l1, l2, negs, pcf);
    }
    float vals[6] = {posg, negg, l1, l2, negs, pcf};
    __shared__ float sb[6][4];
    int lane = threadIdx.x & 63, wid = threadIdx.x >> 6;
#pragma unroll
    for (int k = 0; k < 6; k++) {
        float v = vals[k];
        for (int o = 32; o; o >>= 1) v += __shfl_xor(v, o);
        if (!lane) sb[k][wid] = v;
    }
    __syncthreads();
    if (threadIdx.x < 6) {
        float r = sb[threadIdx.x][0] + sb[threadIdx.x][1] + sb[threadIdx.x][2] + sb[threadIdx.x][3];
        atomicAdd(ws + OFF_ACC + (size_t)b * 6 + threadIdx.x, r);
    }
}

// ---------------- K4: final scalar combine ----------------
__global__ void finalize(float* __restrict__ out, const float* __restrict__ ws) {
    if (threadIdx.x != 0) return;
    float gp = 0, gn = 0, lsh = 0;
    for (int b = 0; b < 8; b++) {
        const float* a = ws + OFF_ACC + (size_t)b * 6;
        float pc = a[5];
        float nc = (float)((size_t)LL * SS) - pc;
        gp += a[0] / fmaxf(pc, 1.0f);
        gn += a[1] / fmaxf(nc, 1.0f);
        lsh += (a[2] + a[3]) * 0.5f + a[4] / fmaxf(nc, 1.0f);
    }
    gp *= 0.125f; gn *= 0.125f; lsh *= 0.125f;
    float lgeo = gp + gn;
    float lgw = (0.5f * lgeo + 0.5f * lsh) * 0.5f;
    float clp = ws[OFF_ACCCL + 0] / 8.0f;
    float cln = ws[OFF_ACCCL + 1] / (8.0f * 2040.0f);
    float lcl = (clp + cln) * 0.5f * 0.5f;
    out[OUT_SCAL + 0] = lgw + lcl;  // total
    out[OUT_SCAL + 1] = gp;         // geo_pos_loss
    out[OUT_SCAL + 2] = gn;         // geo_neg_loss
    out[OUT_SCAL + 3] = lsh;        // loss_sharp
    out[OUT_SCAL + 4] = lcl;        // loss_cl
}

extern "C" void kernel_launch(void* const* d_in, const int* in_sizes, int n_in,
                              void* d_out, int out_size, void* d_ws, size_t ws_size,
                              hipStream_t stream) {
    const float* q_geo   = (const float*)d_in[0];
    const float* q_cl    = (const float*)d_in[1];
    const float* geo_pos = (const float*)d_in[2];
    const float* cl_pos  = (const float*)d_in[3];
    const int*   label   = (const int*)d_in[4];
    const int*   idx     = (const int*)d_in[5];
    float* out = (float*)d_out;
    float* ws  = (float*)d_ws;
    float* dot = ws;

    presplit<<<dim3(1025), dim3(256), 0, stream>>>(q_geo, geo_pos, q_cl, cl_pos, idx, out, ws);
    gemm_dot<<<dim3(512), dim3(256), 0, stream>>>(dot, ws);
    mid<<<dim3(528), dim3(256), 0, stream>>>(cl_pos, idx, ws, out);
    main_loss<<<dim3(256, 8), dim3(256), 0, stream>>>(dot, label, out, ws);
    finalize<<<dim3(1), dim3(64), 0, stream>>>(out, ws);
}

// Round 7
// 148.590 us; speedup vs baseline: 1.0221x; 1.0221x over previous
//
#include <hip/hip_runtime.h>
#include <math.h>

// Problem constants
#define BB 8
#define LL 1024
#define SS 1024
#define CC 128
#define NN 8
#define PP 256

static constexpr float EPS       = 1e-6f;
static constexpr float ONE_M_EPS = 1.0f - 1e-6f;
static constexpr float INV_T     = 1.0f / 0.07f;
static constexpr float NLL_MAX   = 13.815511f;    // -log(1e-6)
static constexpr float NLL_MIN   = 1.0000005e-6f; // -log(1-1e-6)

// Workspace layout (float offsets)
static constexpr size_t DOTSZ      = (size_t)BB * LL * SS;   // 8388608
static constexpr size_t OFF_LSER   = DOTSZ;                  // B*L
static constexpr size_t OFF_LSEC   = DOTSZ + 16384;          // B*S
static constexpr size_t OFF_SHARP2 = DOTSZ + 32768;          // B*L
static constexpr size_t OFF_RP     = DOTSZ + 40960;          // rowpart: 8*16*1024*4
static constexpr size_t OFF_CP     = OFF_RP + 524288;        // colpart: 8*16*1024*4
static constexpr size_t OFF_ACC    = OFF_CP + 524288;        // B*6
static constexpr size_t OFF_ACCCL  = OFF_ACC + 48;           // 2
static constexpr size_t OFF_QN     = OFF_ACC + 64;           // 8*128 normalized q_sel

// Output layout (floats): sharp1[8192], cl_pos_save[1024], scalars
static constexpr int OUT_CLSAVE = 8192;
static constexpr int OUT_SCAL   = 9216;

typedef __bf16 bf16x8 __attribute__((ext_vector_type(8)));
typedef float  floatx4 __attribute__((ext_vector_type(4)));

// Split 4 fp32 into packed bf16 hi pairs (RNE) + lo pairs (exact residual, truncated).
__device__ __forceinline__ void split_f4(float4 x,
                                         unsigned& hp0, unsigned& hp1,
                                         unsigned& lp0, unsigned& lp1) {
    unsigned u0 = __builtin_bit_cast(unsigned, x.x);
    unsigned u1 = __builtin_bit_cast(unsigned, x.y);
    unsigned u2 = __builtin_bit_cast(unsigned, x.z);
    unsigned u3 = __builtin_bit_cast(unsigned, x.w);
    unsigned r0 = u0 + 0x7FFFu + ((u0 >> 16) & 1u);
    unsigned r1 = u1 + 0x7FFFu + ((u1 >> 16) & 1u);
    unsigned r2 = u2 + 0x7FFFu + ((u2 >> 16) & 1u);
    unsigned r3 = u3 + 0x7FFFu + ((u3 >> 16) & 1u);
    float s0 = x.x - __builtin_bit_cast(float, r0 & 0xFFFF0000u);
    float s1 = x.y - __builtin_bit_cast(float, r1 & 0xFFFF0000u);
    float s2 = x.z - __builtin_bit_cast(float, r2 & 0xFFFF0000u);
    float s3 = x.w - __builtin_bit_cast(float, r3 & 0xFFFF0000u);
    hp0 = __builtin_amdgcn_perm(r1, r0, 0x07060302u);
    hp1 = __builtin_amdgcn_perm(r3, r2, 0x07060302u);
    lp0 = __builtin_amdgcn_perm(__builtin_bit_cast(unsigned, s1),
                                __builtin_bit_cast(unsigned, s0), 0x07060302u);
    lp1 = __builtin_amdgcn_perm(__builtin_bit_cast(unsigned, s3),
                                __builtin_bit_cast(unsigned, s2), 0x07060302u);
}

// ---------------- K1: LDS-tiled GEMM with split-at-staging (blocks 0..511) + prep (block 512) ----
// 128x128 tile/block, 4 waves (64x64 each), BK=32, double-buffered 2x32KB LDS.
// LDS per kstep buffer: [A 16KB | B 16KB]; per matrix [128 rows][8 chunks of 16B]:
// chunks 0-3 = bf16-hi of the row's 32 k-values, chunks 4-7 = bf16-lo; phys = logical ^ (row&7).
__global__ __launch_bounds__(256, 2) void gemm_dot(const float* __restrict__ A,
                                                   const float* __restrict__ Bm,
                                                   const float* __restrict__ q_cl,
                                                   const float* __restrict__ cl_pos,
                                                   const int* __restrict__ idx,
                                                   float* __restrict__ out,
                                                   float* __restrict__ dot,
                                                   float* __restrict__ ws) {
    __shared__ __align__(16) char lds[2][32768];   // [dbuf][A 16KB | B 16KB]

    int tid  = threadIdx.x;
    int lane = tid & 63;
    int w    = tid >> 6;

    if (blockIdx.x == 512) {
        // ---- prep: zero accumulators, normalize q_sel, write cl_pos_save ----
        if (tid < 52) ws[OFF_ACC + tid] = 0.0f;
        for (int n = w; n < NN; n += 4) {
            int in = idx[n];
            const float* q = q_cl + ((size_t)(n * PP + in)) * CC;
            float2 qv = *(const float2*)(q + 2 * lane);
            float ss = qv.x * qv.x + qv.y * qv.y;
            for (int o = 32; o; o >>= 1) ss += __shfl_xor(ss, o);
            float inv = 1.0f / fmaxf(sqrtf(ss), 1e-12f);
            *(float2*)(ws + OFF_QN + n * 128 + 2 * lane) = make_float2(qv.x * inv, qv.y * inv);
            const float* cp = cl_pos + ((size_t)(n * PP + in)) * CC;
            float2 cv = *(const float2*)(cp + 2 * lane);
            *(float2*)(out + OUT_CLSAVE + n * 128 + 2 * lane) = cv;
        }
        return;
    }

    int t  = blockIdx.x;            // 0..511
    int b  = t >> 6;
    int rm = t & 63;
    int bl = rm >> 3, bs = rm & 7;
    int R0 = bl * 128, C0 = bs * 128;

    const float* Ab = A  + ((size_t)(b * 1024 + R0)) * CC;
    const float* Bb = Bm + ((size_t)(b * 1024 + C0)) * CC;

    // Staging: 1024 8-float units per kstep (A 512 + B 512), 4 per thread.
    // Unit: load 8 fp32 -> split -> hi 16B + lo 16B into swizzled LDS cells.
    const float* srcu[4];
    int hib[4], lob[4];
#pragma unroll
    for (int u = 0; u < 4; u++) {
        int g   = u * 256 + tid;
        int mat = g >> 9;
        int r   = (g >> 2) & 127;
        int c8  = g & 3;
        srcu[u] = (mat ? Bb : Ab) + (size_t)r * CC + c8 * 8;
        int base = mat * 16384 + r * 128;
        int sw   = r & 7;
        hib[u] = base + ((c8 ^ sw) * 16);
        lob[u] = base + (((c8 + 4) ^ sw) * 16);
    }

    int fl   = lane & 15;
    int quad = lane >> 4;
    int wr   = w >> 1, wc = w & 1;
    int Rw   = wr * 64, Cw = wc * 64;

    floatx4 acc[4][4];
#pragma unroll
    for (int i = 0; i < 4; i++)
#pragma unroll
        for (int j = 0; j < 4; j++) acc[i][j] = (floatx4){0.f, 0.f, 0.f, 0.f};

    float4 v0[4], v1[4];
    // prologue: stage kstep 0
#pragma unroll
    for (int u = 0; u < 4; u++) {
        v0[u] = *(const float4*)(srcu[u]);
        v1[u] = *(const float4*)(srcu[u] + 4);
    }
#pragma unroll
    for (int u = 0; u < 4; u++) {
        unsigned h0, h1, h2, h3, l0, l1, l2, l3;
        split_f4(v0[u], h0, h1, l0, l1);
        split_f4(v1[u], h2, h3, l2, l3);
        *(uint4*)(&lds[0][hib[u]]) = make_uint4(h0, h1, h2, h3);
        *(uint4*)(&lds[0][lob[u]]) = make_uint4(l0, l1, l2, l3);
    }
    __syncthreads();

    for (int ks = 0; ks < 4; ks++) {
        int cur = ks & 1;
        if (ks < 3) {
            // issue next-kstep global loads early; latency hides under MFMA below
#pragma unroll
            for (int u = 0; u < 4; u++) {
                v0[u] = *(const float4*)(srcu[u] + (ks + 1) * 32);
                v1[u] = *(const float4*)(srcu[u] + (ks + 1) * 32 + 4);
            }
        }
        const char* la = lds[cur];
        const char* lb = lds[cur] + 16384;
        bf16x8 ah[4], al[4];
#pragma unroll
        for (int mt = 0; mt < 4; mt++) {
            int row = Rw + mt * 16 + fl;
            int sw  = row & 7;
            ah[mt] = *(const bf16x8*)(la + row * 128 + ((quad ^ sw) * 16));
            al[mt] = *(const bf16x8*)(la + row * 128 + (((quad + 4) ^ sw) * 16));
        }
#pragma unroll
        for (int nt = 0; nt < 4; nt++) {
            int row = Cw + nt * 16 + fl;
            int sw  = row & 7;
            bf16x8 bh  = *(const bf16x8*)(lb + row * 128 + ((quad ^ sw) * 16));
            bf16x8 blo = *(const bf16x8*)(lb + row * 128 + (((quad + 4) ^ sw) * 16));
#pragma unroll
            for (int mt = 0; mt < 4; mt++) {
                acc[mt][nt] = __builtin_amdgcn_mfma_f32_16x16x32_bf16(ah[mt], bh,  acc[mt][nt], 0, 0, 0);
                acc[mt][nt] = __builtin_amdgcn_mfma_f32_16x16x32_bf16(ah[mt], blo, acc[mt][nt], 0, 0, 0);
                acc[mt][nt] = __builtin_amdgcn_mfma_f32_16x16x32_bf16(al[mt], bh,  acc[mt][nt], 0, 0, 0);
            }
        }
        if (ks < 3) {
            char* nxt = lds[cur ^ 1];
#pragma unroll
            for (int u = 0; u < 4; u++) {
                unsigned h0, h1, h2, h3, l0, l1, l2, l3;
                split_f4(v0[u], h0, h1, l0, l1);
                split_f4(v1[u], h2, h3, l2, l3);
                *(uint4*)(&nxt[hib[u]]) = make_uint4(h0, h1, h2, h3);
                *(uint4*)(&nxt[lob[u]]) = make_uint4(l0, l1, l2, l3);
            }
        }
        __syncthreads();
    }

    // ---- Store dot tile. C/D layout: col=lane&15, row=quad*4+reg ----
#pragma unroll
    for (int mt = 0; mt < 4; mt++)
#pragma unroll
        for (int nt = 0; nt < 4; nt++) {
            int col = C0 + Cw + nt * 16 + fl;
#pragma unroll
            for (int r = 0; r < 4; r++) {
                int row = R0 + Rw + mt * 16 + quad * 4 + r;
                dot[((size_t)(b * 1024 + row)) * 1024 + col] = acc[mt][nt][r];
            }
        }

    // ---- Fused wave-private tile statistics (64x64 per wave) ----
    int stile = bs * 2 + wc;
    int ltile = bl * 2 + wr;
    float ces[4], cmx[4], csm[4], csq[4];
#pragma unroll
    for (int nt = 0; nt < 4; nt++) { ces[nt] = 0.f; cmx[nt] = -1e30f; csm[nt] = 0.f; csq[nt] = 0.f; }
#pragma unroll
    for (int mt = 0; mt < 4; mt++) {
#pragma unroll
        for (int r = 0; r < 4; r++) {
            float es = 0.f, mx = -1e30f, sm = 0.f, sq = 0.f;
#pragma unroll
            for (int nt = 0; nt < 4; nt++) {
                float d  = acc[mt][nt][r];
                float e  = __expf(d * INV_T);
                float s2 = fmaf(0.5f, d, 0.5f);
                es += e; mx = fmaxf(mx, s2); sm += s2; sq += s2 * s2;
                ces[nt] += e; cmx[nt] = fmaxf(cmx[nt], s2); csm[nt] += s2; csq[nt] += s2 * s2;
            }
            for (int o = 1; o < 16; o <<= 1) {
                es += __shfl_xor(es, o);
                mx = fmaxf(mx, __shfl_xor(mx, o));
                sm += __shfl_xor(sm, o);
                sq += __shfl_xor(sq, o);
            }
            if (fl == 0) {
                int row = R0 + Rw + mt * 16 + quad * 4 + r;
                *(float4*)(ws + OFF_RP + (((size_t)(b * 16 + stile)) * 1024 + row) * 4) =
                    make_float4(es, mx, sm, sq);
            }
        }
    }
#pragma unroll
    for (int nt = 0; nt < 4; nt++) {
        float es = ces[nt], mx = cmx[nt], sm = csm[nt], sq = csq[nt];
        for (int o = 16; o < 64; o <<= 1) {
            es += __shfl_xor(es, o);
            mx = fmaxf(mx, __shfl_xor(mx, o));
            sm += __shfl_xor(sm, o);
            sq += __shfl_xor(sq, o);
        }
        if (quad == 0) {
            int col = C0 + Cw + nt * 16 + fl;
            *(float4*)(ws + OFF_CP + (((size_t)(b * 16 + ltile)) * 1024 + col) * 4) =
                make_float4(es, mx, sm, sq);
        }
    }
}

// ---------------- K2: blocks 0..15 combine+softmax; blocks 16..527 contrast ----------------
__global__ __launch_bounds__(256) void mid(const float* __restrict__ cl_pos,
                                           const int* __restrict__ idx,
                                           float* __restrict__ ws,
                                           float* __restrict__ out) {
    int q   = blockIdx.x;
    int tid = threadIdx.x;
    int lane = tid & 63, wid = tid >> 6;

    if (q < 16) {
        bool docol = (q < 8);
        int b = q & 7;
        const float* part = ws + (docol ? OFF_CP : OFF_RP);
        float* lse = ws + (docol ? OFF_LSEC : OFF_LSER) + (size_t)b * 1024;
        float zs[4];
        float mxall = -1e30f;
#pragma unroll
        for (int r = 0; r < 4; r++) {
            int i = tid + r * 256;
            float es = 0.f, mx = -1e30f, sm = 0.f, sq = 0.f;
#pragma unroll
            for (int t = 0; t < 16; t++) {
                float4 v = *(const float4*)(part + (((size_t)(b * 16 + t)) * 1024 + i) * 4);
                es += v.x; mx = fmaxf(mx, v.y); sm += v.z; sq += v.w;
            }
            float mean = sm * (1.0f / 1024.0f);
            float var  = (sq - sm * sm * (1.0f / 1024.0f)) * (1.0f / 1023.0f);
            zs[r] = (mx - mean) / sqrtf(fmaxf(var, 1e-30f));
            mxall = fmaxf(mxall, zs[r]);
            lse[i] = __logf(es);
        }
        __shared__ float sb[4];
        __shared__ float red;
        float mx = mxall;
        for (int o = 32; o; o >>= 1) mx = fmaxf(mx, __shfl_xor(mx, o));
        if (!lane) sb[wid] = mx;
        __syncthreads();
        if (tid == 0) red = fmaxf(fmaxf(sb[0], sb[1]), fmaxf(sb[2], sb[3]));
        __syncthreads();
        mx = red;
        float e[4]; float smv = 0.f;
#pragma unroll
        for (int r = 0; r < 4; r++) { e[r] = __expf(zs[r] - mx); smv += e[r]; }
        for (int o = 32; o; o >>= 1) smv += __shfl_xor(smv, o);
        __syncthreads();
        if (!lane) sb[wid] = smv;
        __syncthreads();
        if (tid == 0) red = sb[0] + sb[1] + sb[2] + sb[3];
        __syncthreads();
        float inv = 1.0f / red;
        float* dst = docol ? (out + (size_t)b * 1024) : (ws + OFF_SHARP2 + (size_t)b * 1024);
#pragma unroll
        for (int r = 0; r < 4; r++) dst[tid + r * 256] = e[r] * inv;
    } else {
        // ---- contrast: one wave per all_k row j ----
        int j = (q - 16) * 4 + wid;
        int m, p;
        if (j < NN) {
            m = j; p = idx[j];
        } else {
            int jj = j - NN;
            m = jj / (PP - 1);
            p = 1 + (jj - m * (PP - 1));
            if (p == idx[m]) p = 0;
        }
        const float* k = cl_pos + ((size_t)(m * PP + p)) * CC;
        float2 kv = *(const float2*)(k + 2 * lane);
        float ksq = kv.x * kv.x + kv.y * kv.y;
        for (int o = 32; o; o >>= 1) ksq += __shfl_xor(ksq, o);
        float invkn = 1.0f / fmaxf(sqrtf(ksq), 1e-12f);
        float pos = 0.0f, neg = 0.0f;
        if (j < NN) {
            const float2 qv = *(const float2*)(ws + OFF_QN + j * 128 + 2 * lane);
            float dt = qv.x * kv.x + qv.y * kv.y;
            for (int o = 32; o; o >>= 1) dt += __shfl_xor(dt, o);
            float sim = fminf(fmaxf(fmaf(0.5f * invkn, dt, 0.5f), EPS), ONE_M_EPS);
            pos = -__logf(sim);
        } else {
#pragma unroll
            for (int n = 0; n < NN; n++) {
                const float2 qv = *(const float2*)(ws + OFF_QN + n * 128 + 2 * lane);
                float dt = qv.x * kv.x + qv.y * kv.y;
                for (int o = 32; o; o >>= 1) dt += __shfl_xor(dt, o);
                float om = fminf(fmaxf(fmaf(-0.5f * invkn, dt, 0.5f), EPS), ONE_M_EPS);
                neg -= __logf(om);
            }
        }
        __shared__ float cb[2][4];
        if (!lane) { cb[0][wid] = pos; cb[1][wid] = neg; }
        __syncthreads();
        if (tid == 0) {
            float ps = cb[0][0] + cb[0][1] + cb[0][2] + cb[0][3];
            float ng = cb[1][0] + cb[1][1] + cb[1][2] + cb[1][3];
            if (ps != 0.0f) atomicAdd(ws + OFF_ACCCL + 0, ps);
            if (ng != 0.0f) atomicAdd(ws + OFF_ACCCL + 1, ng);
        }
    }
}

// ---------------- K3: main elementwise loss (branchless) ----------------
__device__ __forceinline__ void proc_elem(float d, int lab, float lcj, float sh1j,
                                          float lr, float s2v,
                                          float& posg, float& negg, float& l1, float& l2,
                                          float& negs, float& pcf) {
    float t = lr + lcj - d * (2.0f * INV_T);   // -log(conf_geo)
    float isPos = (lab == 1) ? 1.0f : 0.0f;
    float isNeg = 1.0f - isPos;
    float tp   = fminf(fmaxf(t, NLL_MIN), NLL_MAX);
    float simc = fminf(fmaxf(fmaf(0.5f, d, 0.5f), EPS), ONE_M_EPS);
    float om   = fminf(fmaxf(fmaf(-0.5f, d, 0.5f), EPS), ONE_M_EPS);   // 1-simc exactly
    float nll2 = -__logf(simc);
    float cf   = fminf(fmaxf(__expf(-t), EPS), ONE_M_EPS);
    float nllg = -__logf(1.0f - cf);
    float nlls = -__logf(om);
    posg += isPos * tp;
    l1   += isPos * nll2 * sh1j;
    l2   += isPos * nll2 * s2v;
    pcf  += isPos;
    negg += isNeg * nllg;
    negs += isNeg * nlls;
}

__global__ __launch_bounds__(256) void main_loss(const float* __restrict__ dot,
                                                 const int* __restrict__ label,
                                                 const float* __restrict__ sharp1,
                                                 float* __restrict__ ws) {
    int b = blockIdx.y;
    int l0 = blockIdx.x * 4;
    int s = threadIdx.x * 4;
    float4 lc4 = *(const float4*)(ws + OFF_LSEC + (size_t)b * 1024 + s);
    float4 sh1 = *(const float4*)(sharp1 + (size_t)b * 1024 + s);
    const float* lser = ws + OFF_LSER + (size_t)b * 1024;
    const float* sh2  = ws + OFF_SHARP2 + (size_t)b * 1024;
    float posg = 0, negg = 0, l1 = 0, l2 = 0, negs = 0, pcf = 0;
#pragma unroll
    for (int r = 0; r < 4; r++) {
        int l = l0 + r;
        float lr  = lser[l];
        float s2v = sh2[l];
        size_t base = ((size_t)(b * 1024 + l)) * 1024 + s;
        float4 d4 = *(const float4*)(dot + base);
        int4  lb  = *(const int4*)(label + base);
        proc_elem(d4.x, lb.x, lc4.x, sh1.x, lr, s2v, posg, negg, l1, l2, negs, pcf);
        proc_elem(d4.y, lb.y, lc4.y, sh1.y, lr, s2v, posg, negg, l1, l2, negs, pcf);
        proc_elem(d4.z, lb.z, lc4.z, sh1.z, lr, s2v, posg, negg, l1, l2, negs, pcf);
        proc_elem(d4.w, lb.w, lc4.w, sh1.w, lr, s2v, posg, negg, l1, l2, negs, pcf);
    }
    float vals[6] = {posg, negg, l1, l2, negs, pcf};
    __shared__ float sb[6][4];
    int lane = threadIdx.x & 63, wid = threadIdx.x >> 6;
#pragma unroll
    for (int k = 0; k < 6; k++) {
        float v = vals[k];
        for (int o = 32; o; o >>= 1) v += __shfl_xor(v, o);
        if (!lane) sb[k][wid] = v;
    }
    __syncthreads();
    if (threadIdx.x < 6) {
        float r = sb[threadIdx.x][0] + sb[threadIdx.x][1] + sb[threadIdx.x][2] + sb[threadIdx.x][3];
        atomicAdd(ws + OFF_ACC + (size_t)b * 6 + threadIdx.x, r);
    }
}

// ---------------- K4: final scalar combine ----------------
__global__ void finalize(float* __restrict__ out, const float* __restrict__ ws) {
    if (threadIdx.x != 0) return;
    float gp = 0, gn = 0, lsh = 0;
    for (int b = 0; b < 8; b++) {
        const float* a = ws + OFF_ACC + (size_t)b * 6;
        float pc = a[5];
        float nc = (float)((size_t)LL * SS) - pc;
        gp += a[0] / fmaxf(pc, 1.0f);
        gn += a[1] / fmaxf(nc, 1.0f);
        lsh += (a[2] + a[3]) * 0.5f + a[4] / fmaxf(nc, 1.0f);
    }
    gp *= 0.125f; gn *= 0.125f; lsh *= 0.125f;
    float lgeo = gp + gn;
    float lgw = (0.5f * lgeo + 0.5f * lsh) * 0.5f;
    float clp = ws[OFF_ACCCL + 0] / 8.0f;
    float cln = ws[OFF_ACCCL + 1] / (8.0f * 2040.0f);
    float lcl = (clp + cln) * 0.5f * 0.5f;
    out[OUT_SCAL + 0] = lgw + lcl;  // total
    out[OUT_SCAL + 1] = gp;         // geo_pos_loss
    out[OUT_SCAL + 2] = gn;         // geo_neg_loss
    out[OUT_SCAL + 3] = lsh;        // loss_sharp
    out[OUT_SCAL + 4] = lcl;        // loss_cl
}

extern "C" void kernel_launch(void* const* d_in, const int* in_sizes, int n_in,
                              void* d_out, int out_size, void* d_ws, size_t ws_size,
                              hipStream_t stream) {
    const float* q_geo   = (const float*)d_in[0];
    const float* q_cl    = (const float*)d_in[1];
    const float* geo_pos = (const float*)d_in[2];
    const float* cl_pos  = (const float*)d_in[3];
    const int*   label   = (const int*)d_in[4];
    const int*   idx     = (const int*)d_in[5];
    float* out = (float*)d_out;
    float* ws  = (float*)d_ws;
    float* dot = ws;

    gemm_dot<<<dim3(513), dim3(256), 0, stream>>>(q_geo, geo_pos, q_cl, cl_pos, idx, out, dot, ws);
    mid<<<dim3(528), dim3(256), 0, stream>>>(cl_pos, idx, ws, out);
    main_loss<<<dim3(256, 8), dim3(256), 0, stream>>>(dot, label, out, ws);
    finalize<<<dim3(1), dim3(64), 0, stream>>>(out, ws);
}